// Round 10
// baseline (1427688.184 us; speedup 1.0000x reference)
//
#include <hip/hip_runtime.h>
#include <hip/hip_bf16.h>
#include <cstdio>

// SHRED: 2-layer LSTM (B=64,T=512,I=64,H=512) + MLP decoder 512->1024->2048->16384.
//
// Round 10: single-XCD persistent recurrence, FIXED coherence + liveness.
//   R9 hung: sc0-only loads may hit stale per-CU cache lines (SC0 alone is not
//   a guaranteed L0/L1 bypass), so the flag poll never saw updates. Fixes:
//   (1) buffer_inv sc0 (CU-cache invalidate, L2 untouched) inside the poll loop
//       and hence before staging reads -> loads served by XCD-L2 (the intra-XCD
//       coherence point). Stores are write-through to L2 on CDNA.
//   (2) All spins get s_sleep backoff + iteration caps -> worst case wrong
//       output (absmax = diagnostic), never a timeout.
//   (3) Poll by wave 0 only (R8-proven), single vmcnt(0) staging.
// Architecture (R9): 256 WGs launched; 32 WGs on ONE XCD elected via
//   s_getreg(HW_REG_XCC_ID) + agent-scope registration; losers exit. Winner
//   wave wid=rank*4+v owns L0 utile wid AND L1 utile wid for all 64 batch rows.
//   Weights: 50 bf16x8 frags/lane in registers. h: staged per step into 128KiB
//   LDS (XOR-swizzled), shared by 4 waves. Flags+h all sc0 (XCD-L2).
//   End: buffer_wbl2 sc1 publishes final h1 to MALL for the decoder.

#define B_  64
#define T_  512
#define I_  64
#define H_  512
#define D1_ 1024
#define D2_ 2048
#define O_  16384

typedef __attribute__((ext_vector_type(8))) short bf16x8_t;
typedef __attribute__((ext_vector_type(4))) float f32x4_t;
typedef unsigned short ushort_t;

__device__ inline ushort_t f2bf(float f) {
    return __builtin_bit_cast(ushort_t, __float2bfloat16(f));
}
__device__ inline float sigm(float x) { return 1.0f / (1.0f + __expf(-x)); }
__device__ inline float tanhf_(float x) {
    float cx = fminf(fmaxf(x, -15.f), 15.f);
    float e = __expf(2.f * cx);
    return (e - 1.f) / (e + 1.f);
}

// ---- prep kernels (unchanged) ----------------------------------------------

__global__ void pack_l0(const float* __restrict__ Wih0, const float* __restrict__ Whh0,
                        ushort_t* __restrict__ pack) {
    int idx = blockIdx.x * 256 + threadIdx.x;       // < 128*18*64
    int l  = idx & 63;
    int kk = (idx >> 6) % 18;
    int tu = idx / (18 * 64);
    int jl = l & 15, g8 = (l >> 4) * 8;
    int gate = jl & 3, u = tu * 4 + (jl >> 2);
    int wrow = gate * H_ + u;
    int kg = kk * 32 + g8;
    const float* s = (kg < H_) ? (Whh0 + (size_t)wrow * H_ + kg)
                               : (Wih0 + (size_t)wrow * I_ + (kg - H_));
    ushort_t* d = pack + (size_t)idx * 8;
#pragma unroll
    for (int i = 0; i < 8; i++) d[i] = f2bf(s[i]);
}

__global__ void pack_l1(const float* __restrict__ Wih1, const float* __restrict__ Whh1,
                        ushort_t* __restrict__ pack) {
    int idx = blockIdx.x * 256 + threadIdx.x;       // < 128*32*64
    int l  = idx & 63;
    int kk = (idx >> 6) & 31;
    int tu = idx >> 11;
    int jl = l & 15, g8 = (l >> 4) * 8;
    int gate = jl & 3, u = tu * 4 + (jl >> 2);
    int wrow = gate * H_ + u;
    int kg = kk * 32 + g8;
    const float* s = (kg < H_) ? (Wih1 + (size_t)wrow * H_ + kg)
                               : (Whh1 + (size_t)wrow * H_ + (kg - H_));
    ushort_t* d = pack + (size_t)idx * 8;
#pragma unroll
    for (int i = 0; i < 8; i++) d[i] = f2bf(s[i]);
}

__global__ void pack_bias(const float* __restrict__ bih0, const float* __restrict__ bhh0,
                          const float* __restrict__ bih1, const float* __restrict__ bhh1,
                          float* __restrict__ bsum) {
    int idx = blockIdx.x * 256 + threadIdx.x;       // < 4096
    int layer = idx >> 11;
    int rest = idx & 2047;
    int u = rest >> 2, gate = rest & 3;
    const float* a = layer ? bih1 : bih0;
    const float* b = layer ? bhh1 : bhh0;
    bsum[idx] = a[gate * H_ + u] + b[gate * H_ + u];
}

__global__ void conv_x(const float* __restrict__ x, ushort_t* __restrict__ xbf) {
    int idx = blockIdx.x * 256 + threadIdx.x;       // < 64*512*64
    int c = idx & 63;
    int t = (idx >> 6) & 511;
    int b = idx >> 15;
    xbf[(size_t)t * 4096 + b * 64 + c] = f2bf(x[idx]);
}

// ---- single-XCD persistent recurrent kernel --------------------------------

#define MFMA_(a, b, c) __builtin_amdgcn_mfma_f32_16x16x32_bf16((a), (b), (c), 0, 0, 0)
#define ELECT_CAP (1 << 20)
#define POLL_CAP  (1 << 16)

__global__ __launch_bounds__(256, 1) void lstm_persist(
    const ushort_t* __restrict__ packL0, const ushort_t* __restrict__ packL1,
    const float* __restrict__ bsum, const ushort_t* __restrict__ xbf,
    ushort_t* __restrict__ hbuf0, ushort_t* __restrict__ hbuf1,
    unsigned int* __restrict__ flags, unsigned int* __restrict__ elect)
{
    __shared__ uint4 hLDS[8192];        // 128 KiB: [0,64K)=h0, [64K,128K)=h1
    __shared__ unsigned int meta[2];
    const int tid = threadIdx.x;

    // ---- election: find 32 WGs on one XCD (agent atomics = MALL-coherent) ----
    unsigned int xcc;
    asm volatile("s_getreg_b32 %0, hwreg(HW_REG_XCC_ID)" : "=s"(xcc));
    if (tid == 0) {
        unsigned int slot = __hip_atomic_fetch_add(&elect[xcc], 1u,
                              __ATOMIC_RELAXED, __HIP_MEMORY_SCOPE_AGENT);
        if (slot == 31u) {                      // this XCD just got its 32nd WG
            unsigned int exp = 0u;
            __hip_atomic_compare_exchange_strong(&elect[8], &exp, xcc + 1u,
                __ATOMIC_RELAXED, __ATOMIC_RELAXED, __HIP_MEMORY_SCOPE_AGENT);
        }
        unsigned int ch = 0u;
        for (int sp = 0; sp < ELECT_CAP; ++sp) {
            ch = __hip_atomic_load(&elect[8], __ATOMIC_RELAXED,
                                   __HIP_MEMORY_SCOPE_AGENT);
            if (ch != 0u) break;
            __builtin_amdgcn_s_sleep(8);
        }
        meta[0] = slot; meta[1] = ch;
    }
    __syncthreads();
    unsigned int slotv = meta[0], chv = meta[1];
    if (chv != xcc + 1u || slotv >= 32u) return;    // losers / cap-trip exit
    const int rank = (int)slotv;

    const int l = tid & 63, v = tid >> 6;
    const int wid = rank * 4 + v;                   // 0..127: utile for BOTH layers
    const int lane15 = l & 15, u_loc = l >> 4, g8 = u_loc * 8;
    const int u = wid * 4 + u_loc;

    // ---- weights -> registers (1 wave/SIMD => full unified budget) ----
    bf16x8_t aW0[18], aW1[32];
    {
        const ushort_t* s0 = packL0 + (size_t)wid * (18 * 512) + l * 8;
#pragma unroll
        for (int kk = 0; kk < 18; ++kk) aW0[kk] = *(const bf16x8_t*)(s0 + kk * 512);
        const ushort_t* s1 = packL1 + (size_t)wid * (32 * 512) + l * 8;
#pragma unroll
        for (int kk = 0; kk < 32; ++kk) aW1[kk] = *(const bf16x8_t*)(s1 + kk * 512);
    }
    const float* bp0 = bsum + u * 4;
    const float* bp1 = bsum + 2048 + u * 4;
    const float b00 = bp0[0], b01 = bp0[1], b02 = bp0[2], b03 = bp0[3];
    const float b10 = bp1[0], b11 = bp1[1], b12 = bp1[2], b13 = bp1[3];
    float c0r[4] = {0.f, 0.f, 0.f, 0.f};
    float c1r[4] = {0.f, 0.f, 0.f, 0.f};

    asm volatile("s_waitcnt vmcnt(0)" ::: "memory");
    __syncthreads();

    const int HS = 64 * 512;
    for (int k = 0; k <= T_; ++k) {
        // ---- poll (wave 0 only): all 128 waves finished step k-1 ----
        if (k > 0) {
            if (v == 0) {
                unsigned int tgt = (unsigned int)k;
                const uint2* fp = (const uint2*)flags;  // lane covers 2 flags
                for (int sp = 0; sp < POLL_CAP; ++sp) {
                    asm volatile("buffer_inv sc0" ::: "memory");   // drop stale L0/L1
                    uint2 f;
                    asm volatile("global_load_dwordx2 %0, %1, off sc0"
                                 : "=v"(f) : "v"(fp + l));
                    asm volatile("s_waitcnt vmcnt(0)" ::: "memory");
                    if (__all((f.x >= tgt) & (f.y >= tgt))) break;
                    __builtin_amdgcn_s_sleep(2);
                }
            }
            __syncthreads();    // release waves 1-3; CU L0/L1 now clean of h lines
        }
        // ---- stage h0[k-1] (slot (k+1)&1) and h1[k-2] (slot k&1) into LDS ----
        {
            const uint4* g0 = (const uint4*)(hbuf0 + ((k + 1) & 1) * HS);
            const uint4* g1 = (const uint4*)(hbuf1 + (k & 1) * HS);
            uint4 tA[16], tB[16];
#pragma unroll
            for (int j = 0; j < 16; ++j)
                asm volatile("global_load_dwordx4 %0, %1, off sc0"
                             : "=v"(tA[j]) : "v"(g0 + j * 256 + tid));
#pragma unroll
            for (int j = 0; j < 16; ++j)
                asm volatile("global_load_dwordx4 %0, %1, off sc0"
                             : "=v"(tB[j]) : "v"(g1 + j * 256 + tid));
            asm volatile("s_waitcnt vmcnt(0)" ::: "memory");
            __builtin_amdgcn_sched_barrier(0);
#pragma unroll
            for (int j = 0; j < 16; ++j) {
                int idx = j * 256 + tid, bb = idx >> 6, boff = (idx & 63) << 4;
                *(uint4*)((char*)hLDS + bb * 1024 + (boff ^ ((bb & 7) << 4))) = tA[j];
            }
#pragma unroll
            for (int j = 0; j < 16; ++j) {
                int idx = j * 256 + tid, bb = idx >> 6, boff = (idx & 63) << 4;
                *(uint4*)((char*)hLDS + 65536 + bb * 1024 + (boff ^ ((bb & 7) << 4))) = tB[j];
            }
        }
        __syncthreads();

        // ---- compute: L0 utile wid (k<512), L1 utile wid (k>=1), 4 bb-blocks
        const bool doL0 = (k < T_), doL1 = (k >= 1);
        ushort_t* hw0 = hbuf0 + (k & 1) * HS;
        ushort_t* hw1 = hbuf1 + ((k + 1) & 1) * HS;
        const ushort_t* xr = xbf + (size_t)k * 4096;
#pragma unroll
        for (int bbb = 0; bbb < 4; ++bbb) {
            const int bb = bbb * 16 + lane15;
            const char* ld0 = (const char*)hLDS + bb * 1024;
            const unsigned int sw = (unsigned int)((bb & 7) << 4);
            bf16x8_t bh0[16];
#pragma unroll
            for (int kk = 0; kk < 16; ++kk)
                bh0[kk] = *(const bf16x8_t*)(ld0 + ((kk * 64 + u_loc * 16) ^ sw));
            if (doL0) {
                f32x4_t accA = {b00, b01, b02, b03};
                f32x4_t accB = {0.f, 0.f, 0.f, 0.f};
#pragma unroll
                for (int kk = 0; kk < 16; ++kk) {
                    if (kk & 1) accB = MFMA_(aW0[kk], bh0[kk], accB);
                    else        accA = MFMA_(aW0[kk], bh0[kk], accA);
                }
                bf16x8_t bx0 = *(const bf16x8_t*)(xr + (size_t)bb * 64 + g8);
                bf16x8_t bx1 = *(const bf16x8_t*)(xr + (size_t)bb * 64 + 32 + g8);
                accA = MFMA_(aW0[16], bx0, accA);
                accB = MFMA_(aW0[17], bx1, accB);
                f32x4_t acc = accA + accB;
                float xi = sigm(acc[0]), xf = sigm(acc[1]);
                float xg = tanhf_(acc[2]), xo = sigm(acc[3]);
                c0r[bbb] = xf * c0r[bbb] + xi * xg;
                float hn = xo * tanhf_(c0r[bbb]);
                unsigned int mine = (unsigned int)f2bf(hn);
                unsigned int other = (unsigned int)__shfl_xor((int)mine, 16, 64);
                if ((u_loc & 1) == 0) {
                    unsigned int valp = mine | (other << 16);
                    const unsigned int* ap =
                        (const unsigned int*)(hw0 + (size_t)bb * 512 + u);
                    asm volatile("global_store_dword %0, %1, off sc0"
                                 :: "v"(ap), "v"(valp) : "memory");
                }
            }
            if (doL1) {
                f32x4_t accA = {b10, b11, b12, b13};
                f32x4_t accB = {0.f, 0.f, 0.f, 0.f};
#pragma unroll
                for (int kk = 0; kk < 16; ++kk) {
                    if (kk & 1) accB = MFMA_(aW1[kk], bh0[kk], accB);
                    else        accA = MFMA_(aW1[kk], bh0[kk], accA);
                }
                bf16x8_t bh1[16];
#pragma unroll
                for (int kk = 0; kk < 16; ++kk)
                    bh1[kk] = *(const bf16x8_t*)(ld0 + 65536 +
                                                 ((kk * 64 + u_loc * 16) ^ sw));
#pragma unroll
                for (int kk = 0; kk < 16; ++kk) {
                    if (kk & 1) accB = MFMA_(aW1[16 + kk], bh1[kk], accB);
                    else        accA = MFMA_(aW1[16 + kk], bh1[kk], accA);
                }
                f32x4_t acc = accA + accB;
                float xi = sigm(acc[0]), xf = sigm(acc[1]);
                float xg = tanhf_(acc[2]), xo = sigm(acc[3]);
                c1r[bbb] = xf * c1r[bbb] + xi * xg;
                float hn = xo * tanhf_(c1r[bbb]);
                unsigned int mine = (unsigned int)f2bf(hn);
                unsigned int other = (unsigned int)__shfl_xor((int)mine, 16, 64);
                if ((u_loc & 1) == 0) {
                    unsigned int valp = mine | (other << 16);
                    const unsigned int* ap =
                        (const unsigned int*)(hw1 + (size_t)bb * 512 + u);
                    asm volatile("global_store_dword %0, %1, off sc0"
                                 :: "v"(ap), "v"(valp) : "memory");
                }
            }
        }
        // ---- publish (per wave, own flag) ----
        if (k < T_) {
            asm volatile("s_waitcnt vmcnt(0)" ::: "memory");    // h stores in L2
            if (l == 0) {
                unsigned int val = (unsigned int)(k + 1);
                const unsigned int* ap = (const unsigned int*)(flags + wid);
                asm volatile("global_store_dword %0, %1, off sc0"
                             :: "v"(ap), "v"(val) : "memory");
            }
        }
        __syncthreads();
    }
    // make dirty L2 h-lines visible device-wide for the decoder kernels
    asm volatile("s_waitcnt vmcnt(0)" ::: "memory");
    asm volatile("buffer_wbl2 sc1" ::: "memory");
    asm volatile("s_waitcnt vmcnt(0)" ::: "memory");
}

// ---- decoder GEMM: out[64][ncols] = act[64][K] @ W[ncols][K]^T + bias ------
template <int NK, bool RELU, bool OUTBF>
__global__ __launch_bounds__(256) void dec_gemm(
    const float* __restrict__ W, const float* __restrict__ bias,
    const ushort_t* __restrict__ act, void* __restrict__ outp, int ncols)
{
    int tile = blockIdx.x, tid = threadIdx.x;
    int l = tid & 63, v = tid >> 6;
    int bb = v * 16 + (l & 15);
    int jA = tile * 16 + (l & 15);
    int g8 = (l >> 4) * 8;
    const float* wrow = W + (size_t)jA * (NK * 32);
    const ushort_t* arow = act + (size_t)bb * (NK * 32);
    f32x4_t acc = {0.f, 0.f, 0.f, 0.f};
    for (int kk = 0; kk < NK; ++kk) {
        int kg = kk * 32 + g8;
        float4 w0 = *(const float4*)(wrow + kg);
        float4 w1 = *(const float4*)(wrow + kg + 4);
        bf16x8_t af;
        af[0] = (short)f2bf(w0.x); af[1] = (short)f2bf(w0.y);
        af[2] = (short)f2bf(w0.z); af[3] = (short)f2bf(w0.w);
        af[4] = (short)f2bf(w1.x); af[5] = (short)f2bf(w1.y);
        af[6] = (short)f2bf(w1.z); af[7] = (short)f2bf(w1.w);
        bf16x8_t bf = *(const bf16x8_t*)(arow + kg);
        acc = __builtin_amdgcn_mfma_f32_16x16x32_bf16(af, bf, acc, 0, 0, 0);
    }
    int j0 = tile * 16 + (l >> 4) * 4;
    float r[4];
#pragma unroll
    for (int i = 0; i < 4; i++) {
        r[i] = acc[i] + bias[j0 + i];
        if (RELU) r[i] = fmaxf(r[i], 0.f);
    }
    if (OUTBF) {
        ushort_t* o = (ushort_t*)outp + (size_t)bb * ncols + j0;
        unsigned int lo = (unsigned)f2bf(r[0]) | ((unsigned)f2bf(r[1]) << 16);
        unsigned int hi = (unsigned)f2bf(r[2]) | ((unsigned)f2bf(r[3]) << 16);
        uint2 q; q.x = lo; q.y = hi;
        *(uint2*)o = q;
    } else {
        float* o = (float*)outp + (size_t)bb * ncols + j0;
        float4 t4; t4.x = r[0]; t4.y = r[1]; t4.z = r[2]; t4.w = r[3];
        *(float4*)o = t4;
    }
}

// ---- host ------------------------------------------------------------------
extern "C" void kernel_launch(void* const* d_in, const int* in_sizes, int n_in,
                              void* d_out, int out_size, void* d_ws, size_t ws_size,
                              hipStream_t stream)
{
    const float* x    = (const float*)d_in[0];
    const float* Wih0 = (const float*)d_in[1];
    const float* Whh0 = (const float*)d_in[2];
    const float* bih0 = (const float*)d_in[3];
    const float* bhh0 = (const float*)d_in[4];
    const float* Wih1 = (const float*)d_in[5];
    const float* Whh1 = (const float*)d_in[6];
    const float* bih1 = (const float*)d_in[7];
    const float* bhh1 = (const float*)d_in[8];
    const float* W1   = (const float*)d_in[9];
    const float* b1   = (const float*)d_in[10];
    const float* W2   = (const float*)d_in[11];
    const float* b2   = (const float*)d_in[12];
    const float* W3   = (const float*)d_in[13];
    const float* b3   = (const float*)d_in[14];

    char* ws = (char*)d_ws;
    size_t off = 0;
    auto take = [&](size_t bytes) -> char* {
        char* p = ws + off;
        off = (off + bytes + 255) & ~(size_t)255;
        return p;
    };
    ushort_t* packL0 = (ushort_t*)take((size_t)128 * 18 * 64 * 8 * 2);  // 2.25 MiB
    ushort_t* packL1 = (ushort_t*)take((size_t)128 * 32 * 64 * 8 * 2);  // 4 MiB
    float*    bsum   = (float*)take(2 * 2048 * 4);
    ushort_t* xbf    = (ushort_t*)take((size_t)512 * 64 * 64 * 2);      // 4 MiB
    char* zbase = ws + off;
    ushort_t* hbuf0  = (ushort_t*)take(2 * 64 * 512 * 2);
    ushort_t* hbuf1  = (ushort_t*)take(2 * 64 * 512 * 2);
    unsigned int* flags = (unsigned int*)take(128 * 4);
    unsigned int* elect = (unsigned int*)take(16 * 4);  // [0..7] cnt, [8] chosen
    size_t zbytes = (size_t)((ws + off) - zbase);
    ushort_t* y1 = (ushort_t*)take(64 * 1024 * 2);
    ushort_t* y2 = (ushort_t*)take(64 * 2048 * 2);
    if (off > ws_size) {
        fprintf(stderr, "kernel_launch: ws too small: need %zu have %zu\n", off, ws_size);
        return;
    }

    // prep (every call; deterministic)
    pack_l0<<<(128 * 18 * 64) / 256, 256, 0, stream>>>(Wih0, Whh0, packL0);
    pack_l1<<<(128 * 32 * 64) / 256, 256, 0, stream>>>(Wih1, Whh1, packL1);
    pack_bias<<<16, 256, 0, stream>>>(bih0, bhh0, bih1, bhh1, bsum);
    conv_x<<<(64 * 512 * 64) / 256, 256, 0, stream>>>(x, xbf);
    hipMemsetAsync(zbase, 0, zbytes, stream);   // zero h rings + flags + elect

    // whole recurrence: 256 WGs launched, 32 co-XCD winners run 513 iterations
    lstm_persist<<<256, 256, 0, stream>>>(packL0, packL1, bsum, xbf,
                                          hbuf0, hbuf1, flags, elect);

    // final top hidden state h1[511] lives in slot 1
    const ushort_t* h1f = hbuf1 + 1 * (64 * 512);
    dec_gemm<16, true,  true ><<<  64, 256, 0, stream>>>(W1, b1, h1f, y1, D1_);
    dec_gemm<32, true,  true ><<< 128, 256, 0, stream>>>(W2, b2, y1, y2, D2_);
    dec_gemm<64, false, false><<<1024, 256, 0, stream>>>(W3, b3, y2, d_out, O_);
}